// Round 1
// baseline (797.831 us; speedup 1.0000x reference)
//
#include <hip/hip_runtime.h>
#include <stdint.h>

#define B_ 4
#define T_ 1024
#define C_ 2048
#define H_ 32
#define HKV_ 8
#define HD_ 64
#define HID_ 5632

typedef __attribute__((ext_vector_type(8))) short short8;
typedef __attribute__((ext_vector_type(4))) float floatx4;

__device__ __forceinline__ float b2f(short s) {
  unsigned u = ((unsigned)(unsigned short)s) << 16;
  return __uint_as_float(u);
}
__device__ __forceinline__ short f2b(float f) {
  unsigned u = __float_as_uint(f);
  u = u + 0x7fffu + ((u >> 16) & 1u);
  return (short)(u >> 16);
}
__device__ __forceinline__ unsigned pk2(float a, float b) {
  return ((unsigned)(unsigned short)f2b(a)) |
         ((unsigned)(unsigned short)f2b(b) << 16);
}

// async global->LDS, 16B per lane, LDS dest = wave-uniform base + lane*16
#define GL2LDS(gp, lp)                                              \
  __builtin_amdgcn_global_load_lds(                                 \
      (const __attribute__((address_space(1))) void*)(gp),          \
      (__attribute__((address_space(3))) void*)(lp), 16, 0, 0)

// ---------------- weight convert + transpose: W[K][N] fp32 -> Wt[N][K] bf16 ----
__global__ __launch_bounds__(256) void convt_kernel(
    const float* __restrict__ W, short* __restrict__ Wt, int K, int N) {
  __shared__ unsigned u[32][65];
  int n0 = blockIdx.x * 64, k0 = blockIdx.y * 64;
  int tx = threadIdx.x & 63, ty = threadIdx.x >> 6;  // ty 0..3
#pragma unroll
  for (int j = 0; j < 8; ++j) {
    int kpair = ty * 8 + j;  // 0..31
    float lo = W[(size_t)(k0 + 2 * kpair) * N + n0 + tx];
    float hi = W[(size_t)(k0 + 2 * kpair + 1) * N + n0 + tx];
    u[kpair][tx] = pk2(lo, hi);
  }
  __syncthreads();
  int ny = threadIdx.x >> 2, kx = threadIdx.x & 3;
  unsigned vals[8];
#pragma unroll
  for (int i = 0; i < 8; ++i) vals[i] = u[kx * 8 + i][ny];
  uint4* dst = (uint4*)(Wt + (size_t)(n0 + ny) * K + k0 + kx * 16);
  dst[0] = make_uint4(vals[0], vals[1], vals[2], vals[3]);
  dst[1] = make_uint4(vals[4], vals[5], vals[6], vals[7]);
}

// ---------------- v transpose: vbuf[bg][t][d] bf16 -> vt[bg][d][t] bf16 -------
__global__ __launch_bounds__(256) void vt_kernel(
    const short* __restrict__ vin, short* __restrict__ vout) {
  __shared__ short t[32][33];
  int t0 = blockIdx.x * 32, d0 = blockIdx.y * 32, bg = blockIdx.z;
  int tx = threadIdx.x & 31, ty = threadIdx.x >> 5;
  const short* src = vin + (size_t)bg * T_ * HD_;
  short* dst = vout + (size_t)bg * T_ * HD_;
#pragma unroll
  for (int j = 0; j < 4; ++j)
    t[ty + j * 8][tx] = src[(size_t)(t0 + ty + j * 8) * HD_ + d0 + tx];
  __syncthreads();
#pragma unroll
  for (int j = 0; j < 4; ++j)
    dst[(size_t)(d0 + ty + j * 8) * T_ + t0 + tx] = t[tx][ty + j * 8];
}

// ---------------- RMSNorm: fp32 row -> bf16 row ----------------
__global__ __launch_bounds__(256) void rmsnorm_kernel(
    const float* __restrict__ x, const float* __restrict__ scale,
    short* __restrict__ out) {
  int row = blockIdx.x, tid = threadIdx.x;
  const float4* xr = (const float4*)(x + (size_t)row * C_);
  float4 v0 = xr[tid], v1 = xr[tid + 256];
  float s = v0.x * v0.x + v0.y * v0.y + v0.z * v0.z + v0.w * v0.w +
            v1.x * v1.x + v1.y * v1.y + v1.z * v1.z + v1.w * v1.w;
  for (int off = 32; off > 0; off >>= 1) s += __shfl_down(s, off, 64);
  __shared__ float red[4];
  if ((tid & 63) == 0) red[tid >> 6] = s;
  __syncthreads();
  float tot = red[0] + red[1] + red[2] + red[3];
  float r = rsqrtf(tot * (1.0f / (float)C_) + 1e-6f);
  const float4* sc = (const float4*)scale;
  float4 s0 = sc[tid], s1 = sc[tid + 256];
  short* o = out + (size_t)row * C_;
  o[tid * 4 + 0] = f2b(v0.x * s0.x * r);
  o[tid * 4 + 1] = f2b(v0.y * s0.y * r);
  o[tid * 4 + 2] = f2b(v0.z * s0.z * r);
  o[tid * 4 + 3] = f2b(v0.w * s0.w * r);
  o[1024 + tid * 4 + 0] = f2b(v1.x * s1.x * r);
  o[1024 + tid * 4 + 1] = f2b(v1.y * s1.y * r);
  o[1024 + tid * 4 + 2] = f2b(v1.z * s1.z * r);
  o[1024 + tid * 4 + 3] = f2b(v1.w * s1.w * r);
}

// ---------------- GEMM 128x128, BK=64 -----------------------------------------
template <int EPI>
__global__ __launch_bounds__(256, 2) void gemm128_kernel(
    const short* __restrict__ A, const short* __restrict__ Bt,
    void* __restrict__ Out, const float* __restrict__ resid,
    int M, int N, int K) {
  __shared__ __align__(16) short smem[16384];
  short* As = smem;
  short* Bs = smem + 8192;
  int tid = threadIdx.x, lane = tid & 63, wave = tid >> 6;
  int quad = lane >> 4, l16 = lane & 15;
  int m0 = blockIdx.y * 128, n0 = blockIdx.x * 128;
  int wm = (wave & 1) * 64, wn = (wave >> 1) * 64;

  const short* ap[4];
  const short* bp[4];
  short* lA[4];
  short* lB[4];
#pragma unroll
  for (int c = 0; c < 4; ++c) {
    int S = wave * 256 + c * 64 + lane;
    int row = S >> 3, kc = ((S & 7) - (row & 7)) & 7;
    ap[c] = A + (size_t)(m0 + row) * K + kc * 8;
    bp[c] = Bt + (size_t)(n0 + row) * K + kc * 8;
    lA[c] = As + (wave * 256 + c * 64) * 8;
    lB[c] = Bs + (wave * 256 + c * 64) * 8;
  }

  int aoff[4], boff[4];
#pragma unroll
  for (int i = 0; i < 4; ++i) {
    int ra = wm + i * 16 + l16;
    aoff[i] = (ra * 8 + ((quad + ra) & 7)) * 8;
    int rb = wn + i * 16 + l16;
    boff[i] = (rb * 8 + ((quad + rb) & 7)) * 8;
  }

  floatx4 acc[4][4] = {};
  for (int k0 = 0; k0 < K; k0 += 64) {
#pragma unroll
    for (int c = 0; c < 4; ++c) {
      GL2LDS(ap[c] + k0, lA[c]);
      GL2LDS(bp[c] + k0, lB[c]);
    }
    __syncthreads();
#pragma unroll
    for (int h = 0; h < 2; ++h) {
      short8 af[4], bf[4];
#pragma unroll
      for (int i = 0; i < 4; ++i) af[i] = *(const short8*)(As + (aoff[i] ^ (h * 32)));
#pragma unroll
      for (int i = 0; i < 4; ++i) bf[i] = *(const short8*)(Bs + (boff[i] ^ (h * 32)));
#pragma unroll
      for (int mi = 0; mi < 4; ++mi)
#pragma unroll
        for (int ni = 0; ni < 4; ++ni)
          acc[mi][ni] = __builtin_amdgcn_mfma_f32_16x16x32_bf16(
              af[mi], bf[ni], acc[mi][ni], 0, 0, 0);
    }
    __syncthreads();
  }
#pragma unroll
  for (int mi = 0; mi < 4; ++mi)
#pragma unroll
    for (int ni = 0; ni < 4; ++ni)
#pragma unroll
      for (int r = 0; r < 4; ++r) {
        int row = m0 + wm + mi * 16 + quad * 4 + r;
        int col = n0 + wn + ni * 16 + l16;
        size_t idx = (size_t)row * N + col;
        float a = acc[mi][ni][r];
        if constexpr (EPI == 0)
          ((short*)Out)[idx] = f2b(a);
        else
          ((float*)Out)[idx] = resid[idx] + a;
      }
}

// ---------------- fused gate+up GEMM, 256x(128g+128u), 8-phase counted-vmcnt ---
// BM=256 rows of A; B-tile = 128 gate cols stacked on 128 up cols (256 LDS rows).
// 8 waves (2M x 4N), per-wave 128x64.  LDS = 2 K-tile double buffer x (A 32K +
// B 32K) = 128 KiB, 1 block/CU.  Staging units are consumption-aligned
// 128-row quarters; one unit (2 x global_load_lds dwordx4 per thread) staged
// per phase into a region whose last reader finished >=1 phase earlier.
// vmcnt(6) at phases 4/8 covers every read issued 3+ phases after its stage.
// Tail iteration (no prefetch) downgrades ph4 to vmcnt(0) so the ph1-staged
// A_u1(t+1) is actually waited for.
__global__ __launch_bounds__(512, 2) void gateup256_kernel(
    const short* __restrict__ A, const short* __restrict__ Wg,
    const short* __restrict__ Wu, short* __restrict__ act, int K) {
  __shared__ __align__(16) short smem[65536];  // 128 KiB
  const int NT = K >> 6;  // K-tiles of 64
  int tid = threadIdx.x, lane = tid & 63, wave = tid >> 6;
  int quad = lane >> 4, l16 = lane & 15;
  int wr = wave >> 2, wc = wave & 3;  // 2M x 4N
  int m0 = blockIdx.y * 256, n0 = blockIdx.x * 128;

  // stage slots: units 0=A rows{0-63,128-191}, 1=A rows{64-127,192-255},
  //              2=B strips col%64<32,          3=B strips col%64>=32
  const short* srcp[4][2];
  int ldsoff[4][2];  // shorts, relative to buffer base
#pragma unroll
  for (int u = 0; u < 4; ++u)
#pragma unroll
    for (int j = 0; j < 2; ++j) {
      int g = j * 512 + wave * 64 + lane;  // chunk index in unit, 0..1023
      int c = g & 7, rrel = g >> 3;
      int R;
      const short* base;
      if (u < 2) {
        R = (rrel & 63) + (rrel >> 6) * 128 + u * 64;
        base = A + (size_t)(m0 + R) * K;
      } else {
        R = (rrel & 31) + (rrel >> 5) * 64 + (u - 2) * 32;
        base = (R < 128) ? Wg + (size_t)(n0 + R) * K
                         : Wu + (size_t)(n0 + R - 128) * K;
      }
      int kc = (c - (R & 7)) & 7;  // rotation swizzle: LDS[R][c] holds kc=(c-R)&7
      srcp[u][j] = base + kc * 8;
      int rr0 = (j * 512 + wave * 64) >> 3;
      int R0 = (u < 2) ? (rr0 & 63) + (rr0 >> 6) * 128 + u * 64
                       : (rr0 & 31) + (rr0 >> 5) * 64 + (u - 2) * 32;
      ldsoff[u][j] = (u < 2 ? 0 : 16384) + R0 * 64;
    }

#define STG(u, j, par, kt) GL2LDS(srcp[u][j] + (kt), smem + (par)*32768 + ldsoff[u][j])
#define BAR()                           \
  {                                     \
    asm volatile("" ::: "memory");      \
    __builtin_amdgcn_s_barrier();       \
    asm volatile("" ::: "memory");      \
  }
#define LGK0()                                          \
  {                                                     \
    asm volatile("s_waitcnt lgkmcnt(0)" ::: "memory");  \
    __builtin_amdgcn_sched_barrier(0);                  \
  }

  // fragment read offsets (shorts); B offsets include +16384 region base
  int aoff8[8], boff[4];
#pragma unroll
  for (int i = 0; i < 8; ++i) {
    int ra = wr * 128 + i * 16 + l16;
    aoff8[i] = (ra * 8 + ((quad + ra) & 7)) * 8;
  }
#pragma unroll
  for (int i = 0; i < 4; ++i) {
    int rb = wc * 64 + i * 16 + l16;
    boff[i] = 16384 + (rb * 8 + ((quad + rb) & 7)) * 8;
  }

  floatx4 acc[8][4] = {};
  short8 a[4][2], b[4][2];

#define RDA(MB, PAR)                                                       \
  {                                                                        \
    _Pragma("unroll") for (int i = 0; i < 4; ++i)                          \
        _Pragma("unroll") for (int h = 0; h < 2; ++h) a[i][h] =            \
        *(const short8*)(smem + (PAR)*32768 + (aoff8[MB + i] ^ (h * 32))); \
  }
#define RDB(NB, PAR)                                                       \
  {                                                                        \
    _Pragma("unroll") for (int i = 0; i < 2; ++i)                          \
        _Pragma("unroll") for (int h = 0; h < 2; ++h) b[NB + i][h] =       \
        *(const short8*)(smem + (PAR)*32768 + (boff[NB + i] ^ (h * 32)));  \
  }
#define MMA(MB, NB)                                                         \
  {                                                                         \
    __builtin_amdgcn_s_setprio(1);                                          \
    _Pragma("unroll") for (int mi = 0; mi < 4; ++mi)                        \
        _Pragma("unroll") for (int ni = 0; ni < 2; ++ni)                    \
        _Pragma("unroll") for (int h = 0; h < 2; ++h) acc[MB + mi][NB + ni] = \
        __builtin_amdgcn_mfma_f32_16x16x32_bf16(                            \
            a[mi][h], b[NB + ni][h], acc[MB + mi][NB + ni], 0, 0, 0);       \
    __builtin_amdgcn_s_setprio(0);                                          \
  }

  // prologue: tile0 (all units) -> buf0; tile1 (A_u0,B_u0,B_u1) -> buf1
#pragma unroll
  for (int u = 0; u < 4; ++u) {
    STG(u, 0, 0, 0);
    STG(u, 1, 0, 0);
  }
  STG(0, 0, 1, 64); STG(0, 1, 1, 64);
  STG(2, 0, 1, 64); STG(2, 1, 1, 64);
  STG(3, 0, 1, 64); STG(3, 1, 1, 64);
  asm volatile("s_waitcnt vmcnt(6)" ::: "memory");  // tile0 landed
  __builtin_amdgcn_sched_barrier(0);
  BAR();

#pragma unroll 1
  for (int t = 0; t < NT; t += 2) {
    int kt1 = (t + 1) << 6, kt2 = (t + 2) << 6, kt3 = (t + 3) << 6;
    bool pf = (t + 2 < NT);
    // ph1: tile t (buf0) A m0-3 + B n0-1 | stage A_u1(t+1)->buf1
    RDA(0, 0); RDB(0, 0);
    STG(1, 0, 1, kt1); STG(1, 1, 1, kt1);
    BAR(); LGK0();
    MMA(0, 0);
    BAR();
    // ph2: B n2-3 | stage A_u0(t+2)->buf0 (read at ph1)
    RDB(2, 0);
    if (pf) { STG(0, 0, 0, kt2); STG(0, 1, 0, kt2); }
    BAR(); LGK0();
    MMA(0, 2);
    BAR();
    // ph3: A m4-7 | stage B_u0(t+2)->buf0 (read at ph1)
    RDA(4, 0);
    if (pf) { STG(2, 0, 0, kt2); STG(2, 1, 0, kt2); }
    BAR(); LGK0();
    MMA(4, 0);
    BAR();
    // ph4: stage B_u1(t+2)->buf0 (read at ph2) | vmcnt gate for tile t+1
    if (pf) { STG(3, 0, 0, kt2); STG(3, 1, 0, kt2); }
    BAR();
    MMA(4, 2);
    if (pf) {
      asm volatile("s_waitcnt vmcnt(6)" ::: "memory");
    } else {
      asm volatile("s_waitcnt vmcnt(0)" ::: "memory");
    }
    __builtin_amdgcn_sched_barrier(0);
    BAR();
    // ph5: tile t+1 (buf1) A m0-3 + B n0-1 | stage A_u1(t+2)->buf0 (read ph3)
    RDA(0, 1); RDB(0, 1);
    if (pf) { STG(1, 0, 0, kt2); STG(1, 1, 0, kt2); }
    BAR(); LGK0();
    MMA(0, 0);
    BAR();
    // ph6: B n2-3 | stage A_u0(t+3)->buf1 (read ph5)
    RDB(2, 1);
    if (pf) { STG(0, 0, 1, kt3); STG(0, 1, 1, kt3); }
    BAR(); LGK0();
    MMA(0, 2);
    BAR();
    // ph7: A m4-7 | stage B_u0(t+3)->buf1 (read ph5)
    RDA(4, 1);
    if (pf) { STG(2, 0, 1, kt3); STG(2, 1, 1, kt3); }
    BAR(); LGK0();
    MMA(4, 0);
    BAR();
    // ph8: stage B_u1(t+3)->buf1 (read ph6) | vmcnt gate for tile t+2
    if (pf) { STG(3, 0, 1, kt3); STG(3, 1, 1, kt3); }
    BAR();
    MMA(4, 2);
    if (pf) {
      asm volatile("s_waitcnt vmcnt(6)" ::: "memory");
      __builtin_amdgcn_sched_barrier(0);
    }
    BAR();
  }

  // epilogue: up waves (wc>=2) publish bf16 acc via LDS; gate waves fuse silu
  asm volatile("s_waitcnt vmcnt(0)" ::: "memory");
  __syncthreads();
  if (wc >= 2) {
    int exb = (wr * 2 + (wc - 2)) * 8192;  // col-major [64 cols][128 rows]
#pragma unroll
    for (int mi = 0; mi < 8; ++mi)
#pragma unroll
      for (int ni = 0; ni < 4; ++ni)
        *(uint2*)(smem + exb + (ni * 16 + l16) * 128 + mi * 16 + quad * 4) =
            make_uint2(pk2(acc[mi][ni][0], acc[mi][ni][1]),
                       pk2(acc[mi][ni][2], acc[mi][ni][3]));
  }
  __syncthreads();
  if (wc < 2) {
    int exb = (wr * 2 + wc) * 8192;
#pragma unroll
    for (int mi = 0; mi < 8; ++mi)
#pragma unroll
      for (int ni = 0; ni < 4; ++ni) {
        uint2 uv = *(const uint2*)(smem + exb + (ni * 16 + l16) * 128 +
                                   mi * 16 + quad * 4);
        float uu[4] = {b2f((short)(uv.x & 0xffff)), b2f((short)(uv.x >> 16)),
                       b2f((short)(uv.y & 0xffff)), b2f((short)(uv.y >> 16))};
#pragma unroll
        for (int r = 0; r < 4; ++r) {
          float g = acc[mi][ni][r];
          float v = g / (1.0f + __expf(-g)) * uu[r];
          act[(size_t)(m0 + wr * 128 + mi * 16 + quad * 4 + r) * HID_ +
              n0 + wc * 64 + ni * 16 + l16] = f2b(v);
        }
      }
  }
#undef STG
#undef BAR
#undef LGK0
#undef RDA
#undef RDB
#undef MMA
}

// ---------------- RoPE + QKV split (q pre-scaled by 1/8) ----------------------
__global__ __launch_bounds__(256) void rope_kernel(
    const short* __restrict__ qkv, const float* __restrict__ cosp,
    const float* __restrict__ sinp, short* __restrict__ q,
    short* __restrict__ k, short* __restrict__ v) {
  int idx = blockIdx.x * 256 + threadIdx.x;  // (b,t,head,i)
  int i = idx & 31;
  int rest = idx >> 5;
  int head = rest % 48;
  int rest2 = rest / 48;
  int t = rest2 & 1023;
  int b = rest2 >> 10;
  const short* src = qkv + (size_t)(b * T_ + t) * 3072 + head * 64 + 2 * i;
  float e = b2f(src[0]), o = b2f(src[1]);
  if (head < 32) {
    float c = cosp[t * 32 + i], s = sinp[t * 32 + i];
    short* dst = q + ((size_t)(b * 32 + head) * 1024 + t) * 64 + 2 * i;
    dst[0] = f2b((e * c - o * s) * 0.125f);
    dst[1] = f2b((e * s + o * c) * 0.125f);
  } else if (head < 40) {
    float c = cosp[t * 32 + i], s = sinp[t * 32 + i];
    short* dst = k + ((size_t)(b * 8 + (head - 32)) * 1024 + t) * 64 + 2 * i;
    dst[0] = f2b(e * c - o * s);
    dst[1] = f2b(e * s + o * c);
  } else {
    short* dst = v + ((size_t)(b * 8 + (head - 40)) * 1024 + t) * 64 + 2 * i;
    dst[0] = src[0];
    dst[1] = src[1];
  }
}

// ---------------- Flash attention (GQA, causal), S^T/O^T formulation ----------
__global__ __launch_bounds__(256) void attn_kernel(
    const short* __restrict__ q, const short* __restrict__ k,
    const short* __restrict__ vt, short* __restrict__ y) {
  __shared__ __align__(16) short P[4][1024];  // per-wave 16 q x 64 key bf16
  int bx = blockIdx.x, h = blockIdx.y, b = blockIdx.z;
  int lane = threadIdx.x & 63, wave = threadIdx.x >> 6;
  int quad = lane >> 4, l16 = lane & 15;
  int g = h >> 2;
  const short* qp = q + (size_t)(b * H_ + h) * T_ * HD_;
  const short* kp = k + (size_t)(b * HKV_ + g) * T_ * HD_;
  const short* vp = vt + (size_t)(b * HKV_ + g) * T_ * HD_;  // [d][t]
  short* Pw = &P[wave][0];
  int sw = (l16 & 7) << 1;  // even xor keeps b128 pairing + 16B alignment
#pragma unroll 1
  for (int half = 0; half < 2; ++half) {
    int tb = half ? (15 - bx) : bx;
    int q0w = tb * 64 + wave * 16;
    int qidx = q0w + l16;
    short8 qf0 = *(const short8*)(qp + (size_t)(q0w + l16) * HD_ + quad * 8);
    short8 qf1 = *(const short8*)(qp + (size_t)(q0w + l16) * HD_ + 32 + quad * 8);
    floatx4 acc[4] = {};
    float m = -1e30f, l = 0.f;
    for (int k0 = 0; k0 <= q0w; k0 += 64) {
      floatx4 st[4];
#pragma unroll
      for (int kt = 0; kt < 4; ++kt) {
        floatx4 z = {0.f, 0.f, 0.f, 0.f};
        const short* kb = kp + (size_t)(k0 + kt * 16 + l16) * HD_;
        short8 kf0 = *(const short8*)(kb + quad * 8);
        short8 kf1 = *(const short8*)(kb + 32 + quad * 8);
        z = __builtin_amdgcn_mfma_f32_16x16x32_bf16(kf0, qf0, z, 0, 0, 0);
        z = __builtin_amdgcn_mfma_f32_16x16x32_bf16(kf1, qf1, z, 0, 0, 0);
        st[kt] = z;
      }
      if (k0 + 64 > q0w) {  // only the diagonal iteration needs the causal mask
#pragma unroll
        for (int kt = 0; kt < 4; ++kt)
#pragma unroll
          for (int r = 0; r < 4; ++r)
            if (k0 + kt * 16 + quad * 4 + r > qidx) st[kt][r] = -1e30f;
      }
      float mloc = -1e30f;
#pragma unroll
      for (int kt = 0; kt < 4; ++kt)
#pragma unroll
        for (int r = 0; r < 4; ++r) mloc = fmaxf(mloc, st[kt][r]);
      mloc = fmaxf(mloc, __shfl_xor(mloc, 16, 64));
      mloc = fmaxf(mloc, __shfl_xor(mloc, 32, 64));
      float mn = fmaxf(m, mloc);
      float alpha = __expf(m - mn);
      m = mn;
      float rsum = 0.f;
#pragma unroll
      for (int kt = 0; kt < 4; ++kt)
#pragma unroll
        for (int r = 0; r < 4; ++r) {
          float p = __expf(st[kt][r] - mn);
          st[kt][r] = p;
          rsum += p;
        }
      rsum += __shfl_xor(rsum, 16, 64);
      rsum += __shfl_xor(rsum, 32, 64);
      l = l * alpha + rsum;
#pragma unroll
      for (int mt = 0; mt < 4; ++mt)
#pragma unroll
        for (int r = 0; r < 4; ++r) acc[mt][r] *= alpha;
      // P^T -> LDS as P[q][key], 4 consecutive keys packed per b64 write
#pragma unroll
      for (int kt = 0; kt < 4; ++kt) {
        int hc = (kt * 4 + quad) ^ sw;
        *(uint2*)(Pw + l16 * 64 + hc * 4) =
            make_uint2(pk2(st[kt][0], st[kt][1]), pk2(st[kt][2], st[kt][3]));
      }
#pragma unroll
      for (int chunk = 0; chunk < 2; ++chunk) {
        int hc = (chunk * 8 + quad * 2) ^ sw;
        short8 pf = *(const short8*)(Pw + l16 * 64 + hc * 4);
#pragma unroll
        for (int mt = 0; mt < 4; ++mt) {
          short8 vf = *(const short8*)(vp + (size_t)(mt * 16 + l16) * T_ +
                                       k0 + chunk * 32 + quad * 8);
          acc[mt] =
              __builtin_amdgcn_mfma_f32_16x16x32_bf16(vf, pf, acc[mt], 0, 0, 0);
        }
      }
    }
    // epilogue: O^T/l -> LDS transpose (wave-private) -> coalesced 16B stores
    float inv = 1.0f / l;
#pragma unroll
    for (int mt = 0; mt < 4; ++mt) {
      int hc = (mt * 4 + quad) ^ sw;  // d chunk = mt*16 + quad*4
      *(uint2*)(Pw + l16 * 64 + hc * 4) =
          make_uint2(pk2(acc[mt][0] * inv, acc[mt][1] * inv),
                     pk2(acc[mt][2] * inv, acc[mt][3] * inv));
    }
    uint2 o0 = *(uint2*)(Pw + l16 * 64 + (((quad * 4 + 0) ^ sw) * 4));
    uint2 o1 = *(uint2*)(Pw + l16 * 64 + (((quad * 4 + 1) ^ sw) * 4));
    uint2 o2 = *(uint2*)(Pw + l16 * 64 + (((quad * 4 + 2) ^ sw) * 4));
    uint2 o3 = *(uint2*)(Pw + l16 * 64 + (((quad * 4 + 3) ^ sw) * 4));
    uint4* dst =
        (uint4*)(y + (size_t)(b * T_ + q0w + l16) * C_ + h * 64 + quad * 16);
    dst[0] = make_uint4(o0.x, o0.y, o1.x, o1.y);
    dst[1] = make_uint4(o2.x, o2.y, o3.x, o3.y);
  }
}

extern "C" void kernel_launch(void* const* d_in, const int* in_sizes, int n_in,
                              void* d_out, int out_size, void* d_ws, size_t ws_size,
                              hipStream_t stream) {
  const float* x = (const float*)d_in[0];
  const float* cosp = (const float*)d_in[1];
  const float* sinp = (const float*)d_in[2];
  const float* w_attn = (const float*)d_in[3];
  const float* w_proj = (const float*)d_in[4];
  const float* w_gate = (const float*)d_in[5];
  const float* w_up = (const float*)d_in[6];
  const float* w_down = (const float*)d_in[7];
  const float* scale1 = (const float*)d_in[8];
  const float* scale2 = (const float*)d_in[9];
  float* out = (float*)d_out;
  char* ws = (char*)d_ws;

  // workspace layout (bytes), peak 113,246,208:
  short* S1 = (short*)(ws + 0);            // 23,068,672  wt_gate -> wt_down
  short* S2 = (short*)(ws + 23068672);     // 23,068,672  wt_up
  short* hbuf = (short*)(ws + 46137344);   // 16,777,216  h -> q -> h2
  short* S0 = (short*)(ws + 62914560);     // 12,582,912  wt_attn -> wt_proj
  short* qkv = (short*)(ws + 75497472);    // 25,165,824  qkv -> y
  short* kbuf = (short*)(ws + 100663296);  //  4,194,304
  short* vbuf = (short*)(ws + 104857600);  //  4,194,304
  short* vtbuf = (short*)(ws + 109051904); //  4,194,304  v transposed [bg][d][t]
  short* act = (short*)(ws + 62914560);    // 46,137,344  over S0+qkv+k+v (dead)

  convt_kernel<<<dim3(3072 / 64, 2048 / 64), 256, 0, stream>>>(w_attn, S0, 2048, 3072);
  rmsnorm_kernel<<<4096, 256, 0, stream>>>(x, scale1, hbuf);
  gemm128_kernel<0><<<dim3(3072 / 128, 4096 / 128), 256, 0, stream>>>(
      hbuf, S0, qkv, nullptr, 4096, 3072, 2048);
  rope_kernel<<<24576, 256, 0, stream>>>(qkv, cosp, sinp, hbuf, kbuf, vbuf);
  vt_kernel<<<dim3(32, 2, 32), 256, 0, stream>>>(vbuf, vtbuf);
  attn_kernel<<<dim3(8, 32, 4), 256, 0, stream>>>(hbuf, kbuf, vtbuf, qkv);
  convt_kernel<<<dim3(2048 / 64, 2048 / 64), 256, 0, stream>>>(w_proj, S0, 2048, 2048);
  gemm128_kernel<1><<<dim3(2048 / 128, 4096 / 128), 256, 0, stream>>>(
      qkv, S0, out, x, 4096, 2048, 2048);
  rmsnorm_kernel<<<4096, 256, 0, stream>>>(out, scale2, hbuf);
  convt_kernel<<<dim3(5632 / 64, 2048 / 64), 256, 0, stream>>>(w_gate, S1, 2048, 5632);
  convt_kernel<<<dim3(5632 / 64, 2048 / 64), 256, 0, stream>>>(w_up, S2, 2048, 5632);
  gateup256_kernel<<<dim3(5632 / 128, 4096 / 256), 512, 0, stream>>>(
      hbuf, S1, S2, act, 2048);
  convt_kernel<<<dim3(2048 / 64, 5632 / 64), 256, 0, stream>>>(w_down, S1, 5632, 2048);
  gemm128_kernel<1><<<dim3(2048 / 128, 4096 / 128), 256, 0, stream>>>(
      act, S1, out, out, 4096, 2048, 5632);
}